// Round 3
// baseline (241.931 us; speedup 1.0000x reference)
//
#include <hip/hip_runtime.h>

#define HIDDEN 64
#define HALFD  32
#define VOCAB  64
#define BATCH  256
#define SEQLEN 2048

#define RLF(v, sl) __int_as_float(__builtin_amdgcn_readlane(__float_as_int(v), (sl)))
#define RLI(v, sl) __builtin_amdgcn_readlane((v), (sl))
#define GIX(j,m) (((j)==0?0:(j)==1?7:(j)==2?13:(j)==3?18:(j)==4?22:(j)==5?25:27) + (m) - (j) - 1)
#define OM(m) (((m)*((m)+1))>>1)

// ---------------------------------------------------------------------------
// Kernel 1: per-token vocab tables.
//   ws[0    ..2047]  ks_voc [64][32]  (normalized hs)
//   ws[2048 ..4095]  ke_voc [64][32]  (normalized he)
//   ws[4096 ..6143]  vs_voc [64][32]  (raw hs)
//   ws[6144 ..8191]  ve_voc [64][32]  (raw he)
//   ws[8192 ..16383] Gs,Ge [2][64][64]
// ---------------------------------------------------------------------------
__global__ __launch_bounds__(64) void vocab_kernel(
    const float* __restrict__ embed, const float* __restrict__ W1, const float* __restrict__ b1,
    const float* __restrict__ W2, const float* __restrict__ b2,
    const float* __restrict__ ln_g, const float* __restrict__ ln_b,
    const float* __restrict__ Ws, const float* __restrict__ bs,
    const float* __restrict__ We, const float* __restrict__ be,
    float* __restrict__ ws)
{
    const int v = blockIdx.x;
    const int tid = threadIdx.x;

    __shared__ float e_s[64];
    __shared__ float a1_s[128];
    __shared__ float h_s[64];

    e_s[tid] = embed[v * 64 + tid];
    __syncthreads();

    float p0 = b1[tid], p1 = 0.f, p2 = 0.f, p3 = 0.f;
    float q0 = b1[tid + 64], q1 = 0.f, q2 = 0.f, q3 = 0.f;
    #pragma unroll
    for (int m = 0; m < 64; m += 4) {
        p0 = fmaf(e_s[m],   W1[tid * 64 + m],     p0);
        p1 = fmaf(e_s[m+1], W1[tid * 64 + m + 1], p1);
        p2 = fmaf(e_s[m+2], W1[tid * 64 + m + 2], p2);
        p3 = fmaf(e_s[m+3], W1[tid * 64 + m + 3], p3);
        q0 = fmaf(e_s[m],   W1[(tid + 64) * 64 + m],     q0);
        q1 = fmaf(e_s[m+1], W1[(tid + 64) * 64 + m + 1], q1);
        q2 = fmaf(e_s[m+2], W1[(tid + 64) * 64 + m + 2], q2);
        q3 = fmaf(e_s[m+3], W1[(tid + 64) * 64 + m + 3], q3);
    }
    a1_s[tid]      = fmaxf((p0 + p1) + (p2 + p3), 0.0f);
    a1_s[tid + 64] = fmaxf((q0 + q1) + (q2 + q3), 0.0f);
    __syncthreads();

    float f0 = b2[tid], f1 = 0.f, f2 = 0.f, f3 = 0.f;
    #pragma unroll
    for (int m = 0; m < 128; m += 4) {
        f0 = fmaf(a1_s[m],   W2[tid * 128 + m],     f0);
        f1 = fmaf(a1_s[m+1], W2[tid * 128 + m + 1], f1);
        f2 = fmaf(a1_s[m+2], W2[tid * 128 + m + 2], f2);
        f3 = fmaf(a1_s[m+3], W2[tid * 128 + m + 3], f3);
    }
    float x = e_s[tid] + ((f0 + f1) + (f2 + f3));

    float s = x, s2 = x * x;
    #pragma unroll
    for (int off = 32; off >= 1; off >>= 1) {
        s  += __shfl_xor(s,  off, 64);
        s2 += __shfl_xor(s2, off, 64);
    }
    float mu  = s * (1.0f / 64.0f);
    float var = s2 * (1.0f / 64.0f) - mu * mu;
    float hval = (x - mu) * rsqrtf(var + 1e-5f) * ln_g[tid] + ln_b[tid];
    h_s[tid] = hval;
    __syncthreads();

    const int j = tid & 31;
    const bool is_s = tid < 32;
    const float* W = is_s ? Ws : We;
    float c0 = is_s ? bs[j] : be[j];
    float c1 = 0.f, c2 = 0.f, c3 = 0.f;
    #pragma unroll
    for (int m = 0; m < 64; m += 4) {
        c0 = fmaf(h_s[m],   W[j * 64 + m],     c0);
        c1 = fmaf(h_s[m+1], W[j * 64 + m + 1], c1);
        c2 = fmaf(h_s[m+2], W[j * 64 + m + 2], c2);
        c3 = fmaf(h_s[m+3], W[j * 64 + m + 3], c3);
    }
    float acc = (c0 + c1) + (c2 + c3);

    float n2 = acc * acc;
    #pragma unroll
    for (int off = 16; off >= 1; off >>= 1) n2 += __shfl_xor(n2, off, 64);
    float norm = sqrtf(n2);
    float kn = acc / fmaxf(norm, 1e-12f);

    const int base = v * 32 + j;
    if (is_s) { ws[base]        = kn; ws[4096 + base] = acc; }
    else      { ws[2048 + base] = kn; ws[6144 + base] = acc; }
}

// ---------------------------------------------------------------------------
// Kernel 1b: Gram tables G_w[a][b] = k_w[a].k_w[b], [64][64] in ws.
// ---------------------------------------------------------------------------
__global__ __launch_bounds__(256) void gram_kernel(float* __restrict__ ws)
{
    const int w   = blockIdx.x & 1;
    const int seg = blockIdx.x >> 1;          // 0..3
    const int tid = threadIdx.x;
    __shared__ float k_s[64][33];
    const float* kb = ws + w * 2048;
    for (int i = tid; i < 2048; i += 256) k_s[i >> 5][i & 31] = kb[i];
    __syncthreads();
    const int a  = seg * 16 + (tid >> 4);
    const int b0 = (tid & 15) << 2;
    float* Gw = ws + 8192 + w * 4096 + a * 64;
    #pragma unroll
    for (int bb = 0; bb < 4; ++bb) {
        const int bcol = b0 + bb;
        float acc0 = 0.f, acc1 = 0.f;
        #pragma unroll
        for (int m = 0; m < 32; m += 2) {
            acc0 = fmaf(k_s[a][m],     k_s[bcol][m],     acc0);
            acc1 = fmaf(k_s[a][m + 1], k_s[bcol][m + 1], acc1);
        }
        Gw[bcol] = acc0 + acc1;
    }
}

// chunk-8 solve-matrix build: s = W t with f folded (verbatim R9 math)
static __device__ __forceinline__ void build_wpack(
    const int* tj, float fb, float invL, bool is_e, bool is_last, float* Wp,
    const float* __restrict__ Gg)
{
    float f[8];
    #pragma unroll
    for (int j = 0; j < 8; ++j) f[j] = is_e ? (fb + (float)j * invL) : 1.0f;
    if (is_last) f[7] = 0.0f;     // position 2047 is the query, not a write

    float g[28];
    #pragma unroll
    for (int j = 0; j < 7; ++j)
        #pragma unroll
        for (int m = j + 1; m < 8; ++m) g[GIX(j, m)] = Gg[tj[j] * 64 + tj[m]];

    #pragma unroll
    for (int m = 0; m < 8; ++m) {
        float col[8];
        col[m] = f[m];
        #pragma unroll
        for (int j = 6; j >= 0; --j) {
            if (j < m) {
                float acc = 0.0f;
                #pragma unroll
                for (int p = 1; p < 8; ++p)
                    if (p > j && p <= m) acc = fmaf(g[GIX(j, p)], col[p], acc);
                col[j] = -f[j] * acc;
            }
        }
        #pragma unroll
        for (int j = 0; j < 8; ++j)
            if (j <= m) Wp[OM(m) + j] = col[j];
    }
}

struct Tok {                // shared between branches (same token sequence)
    int tokv;               // lane-vector: tok[c*8 + (lane&7)]
    int tk[8];              // uniform tokens (SGPR via v_readlane)
};
struct Ch {                 // per-branch chunk state
    float grow[8];          // G[tok_j][lane]
    float R[8];             // per-lane W row (lane l7=i holds row i)
    float braw;             // shfl(u_{c+1}, tok_c), 2-body slack
    float bp[8];            // G[tk_{c+1,j}][tk_{c,l7}], bpermute 1-body early
};

// ---------------------------------------------------------------------------
// Kernel 2 (R19): DUAL-CHAIN SINGLE-WAVE sweep.
// R17/R18 post-mortem: all operands have >=1 body slack, yet ~450 stall
// cyc/body persist -> per-wave unhideable latency (readlane SGPR hazards,
// spine chain, waitcnt boundaries, bpermute return). Single-wave-per-SIMD
// cannot fill these. Fix: merge BOTH branch chains (s,e) into ONE wave —
// independent instruction streams interleaved section-by-section, so each
// chain's latency is covered by the other's issue. Token pipeline (tokv/tk/
// tv2/tv3) and wacc compares dedup across chains. bp uses the cheap
// bpermute form, issued EARLY in the body (needs only cur.grow [1 body old]
// + nxt.tokv). Block = 64 threads; 256 blocks; 1 wave/CU; LDS 140 KB.
// ---------------------------------------------------------------------------
__global__ __launch_bounds__(64) void scan_kernel(
    const int* __restrict__ seq, const float* __restrict__ ws,
    const float* __restrict__ Wrp, const float* __restrict__ brp,
    const float* __restrict__ Wo, const float* __restrict__ bo,
    float* __restrict__ out)
{
    const int b    = blockIdx.x;
    const int lane = threadIdx.x;        // 0..63
    const int l7   = lane & 7;

    __shared__ __align__(16) float Wlds[2][256][8][8];   // 128 KB
    __shared__ __align__(16) int   toklds[SEQLEN];       // 8 KB (prologue only)
    __shared__ float wacc_s[2][64];
    __shared__ float r_s[64];
    __shared__ float t1_s[64];

    const float* GgS = ws + 8192;
    const float* GgE = ws + 8192 + 4096;
    const int*   sq  = seq + b * SEQLEN;

    // ---- stage token sequence ----
    {
        const int4* sq4 = (const int4*)sq;
        int4* tl = (int4*)toklds;
        #pragma unroll
        for (int i = 0; i < 8; ++i) tl[lane + i * 64] = sq4[lane + i * 64];
    }
    __syncthreads();

    // ---- precompute W row-tables: 8 builds/lane (2 branches x 4 chunks) ----
    {
        const float invL = 1.0f / (float)SEQLEN;
        #pragma unroll
        for (int w = 0; w < 2; ++w) {
            const float* Gg = (w == 0) ? GgS : GgE;
            #pragma unroll
            for (int qq = 0; qq < 4; ++qq) {
                const int c = lane + (qq << 6);
                int tj[8];
                #pragma unroll
                for (int j = 0; j < 8; ++j) tj[j] = toklds[c * 8 + j];
                float Wp[36];
                build_wpack(tj, (float)(8 * c + 1) * invL, invL, (w == 1), c == 255, Wp, Gg);
                const int cx = c & 7;
                #pragma unroll
                for (int i = 0; i < 8; ++i) {
                    float r[8];
                    #pragma unroll
                    for (int m = 0; m < 8; ++m) r[m] = (m >= i) ? Wp[OM(m) + i] : 0.0f;
                    float4* dst = (float4*)&Wlds[w][c][i ^ cx][0];
                    dst[0] = make_float4(r[0], r[1], r[2], r[3]);
                    dst[1] = make_float4(r[4], r[5], r[6], r[7]);
                }
            }
        }
    }
    __syncthreads();

    // ---- serial backward sweep: dual chain, single wave ----
    Tok TA, TB;
    Ch  SA, SB, EA, EB;
    float uS, uE;
    float waccS0 = 0.f, waccS1 = 0.f, waccE0 = 0.f, waccE1 = 0.f;
    float spS0, spS1, spS2, spS3, spS4, spS5, spS6, spS7;
    float spE0, spE1, spE2, spE3, spE4, spE5, spE6, spE7;
    int tv2;

    // prologue: chunk 255 full; 254 tokens + braw; 253 tokens
    TA.tokv = sq[2040 + l7];
    TB.tokv = sq[2032 + l7];
    tv2     = sq[2024 + l7];
    #pragma unroll
    for (int j = 0; j < 8; ++j) TA.tk[j] = RLI(TA.tokv, j);
    #pragma unroll
    for (int j = 0; j < 8; ++j) SA.grow[j] = GgS[TA.tk[j] * 64 + lane];
    #pragma unroll
    for (int j = 0; j < 8; ++j) EA.grow[j] = GgE[TA.tk[j] * 64 + lane];
    {
        const float4* rp = (const float4*)&Wlds[0][255][l7 ^ 7][0];
        float4 lo = rp[0], hi = rp[1];
        SA.R[0] = lo.x; SA.R[1] = lo.y; SA.R[2] = lo.z; SA.R[3] = lo.w;
        SA.R[4] = hi.x; SA.R[5] = hi.y; SA.R[6] = hi.z; SA.R[7] = hi.w;
        const float4* rq = (const float4*)&Wlds[1][255][l7 ^ 7][0];
        float4 lo2 = rq[0], hi2 = rq[1];
        EA.R[0] = lo2.x; EA.R[1] = lo2.y; EA.R[2] = lo2.z; EA.R[3] = lo2.w;
        EA.R[4] = hi2.x; EA.R[5] = hi2.y; EA.R[6] = hi2.z; EA.R[7] = hi2.w;
    }
    uS = GgS[TA.tk[7] * 64 + lane];          // query token = position 2047
    uE = GgE[TA.tk[7] * 64 + lane];
    SA.braw = __shfl(uS, TA.tokv, 64);
    SB.braw = __shfl(uS, TB.tokv, 64);
    EA.braw = __shfl(uE, TA.tokv, 64);
    EB.braw = __shfl(uE, TB.tokv, 64);
    #pragma unroll
    for (int j = 0; j < 8; ++j) { SA.bp[j] = 0.0f; EA.bp[j] = 0.0f; }
    spS0=spS1=spS2=spS3=spS4=spS5=spS6=spS7 = 0.0f;
    spE0=spE1=spE2=spE3=spE4=spE5=spE6=spE7 = 0.0f;

    auto body2 = [&](Tok& cT, Tok& nT, Ch& cS, Ch& nS, Ch& cE, Ch& nE, int c) {
        const int cm1 = (c > 0) ? c - 1 : 0;
        const int cm3 = (c > 2) ? c - 3 : 0;

        // ==== spine heads: corrected gathers (both chains) ====
        float x01 = fmaf(cS.bp[1], spS1, cS.bp[0] * spS0);
        float x23 = fmaf(cS.bp[3], spS3, cS.bp[2] * spS2);
        float x45 = fmaf(cS.bp[5], spS5, cS.bp[4] * spS4);
        float x67 = fmaf(cS.bp[7], spS7, cS.bp[6] * spS6);
        float tlS = cS.braw - ((x01 + x23) + (x45 + x67));
        float y01 = fmaf(cE.bp[1], spE1, cE.bp[0] * spE0);
        float y23 = fmaf(cE.bp[3], spE3, cE.bp[2] * spE2);
        float y45 = fmaf(cE.bp[5], spE5, cE.bp[4] * spE4);
        float y67 = fmaf(cE.bp[7], spE7, cE.bp[6] * spE6);
        float tlE = cE.braw - ((y01 + y23) + (y45 + y67));

        float tS0 = RLF(tlS, 0), tS1 = RLF(tlS, 1), tS2 = RLF(tlS, 2), tS3 = RLF(tlS, 3);
        float tS4 = RLF(tlS, 4), tS5 = RLF(tlS, 5), tS6 = RLF(tlS, 6), tS7 = RLF(tlS, 7);
        float tE0 = RLF(tlE, 0), tE1 = RLF(tlE, 1), tE2 = RLF(tlE, 2), tE3 = RLF(tlE, 3);
        float tE4 = RLF(tlE, 4), tE5 = RLF(tlE, 5), tE6 = RLF(tlE, 6), tE7 = RLF(tlE, 7);

        // ==== EARLY bp bpermutes for chunk c-1 (cur.grow is a body old) ====
        #pragma unroll
        for (int j = 0; j < 8; ++j) nS.bp[j] = __shfl(cS.grow[j], nT.tokv, 64);
        #pragma unroll
        for (int j = 0; j < 8; ++j) nE.bp[j] = __shfl(cE.grow[j], nT.tokv, 64);

        // ==== prefetch chunk c-1 (shared tokens; both chains' tables) ====
        #pragma unroll
        for (int j = 0; j < 8; ++j) nT.tk[j] = RLI(nT.tokv, j);
        #pragma unroll
        for (int j = 0; j < 8; ++j) nS.grow[j] = GgS[nT.tk[j] * 64 + lane];
        #pragma unroll
        for (int j = 0; j < 8; ++j) nE.grow[j] = GgE[nT.tk[j] * 64 + lane];
        {
            const float4* rp = (const float4*)&Wlds[0][cm1][l7 ^ (cm1 & 7)][0];
            float4 lo = rp[0], hi = rp[1];
            nS.R[0] = lo.x; nS.R[1] = lo.y; nS.R[2] = lo.z; nS.R[3] = lo.w;
            nS.R[4] = hi.x; nS.R[5] = hi.y; nS.R[6] = hi.z; nS.R[7] = hi.w;
            const float4* rq = (const float4*)&Wlds[1][cm1][l7 ^ (cm1 & 7)][0];
            float4 lo2 = rq[0], hi2 = rq[1];
            nE.R[0] = lo2.x; nE.R[1] = lo2.y; nE.R[2] = lo2.z; nE.R[3] = lo2.w;
            nE.R[4] = hi2.x; nE.R[5] = hi2.y; nE.R[6] = hi2.z; nE.R[7] = hi2.w;
        }
        int tv3 = sq[cm3 * 8 + l7];

        // ==== distributed row trees (lane l7=i computes s_i), both chains ====
        float a0 = fmaf(cS.R[1], tS1, cS.R[0] * tS0);
        float a1 = fmaf(cS.R[3], tS3, cS.R[2] * tS2);
        float a2 = fmaf(cS.R[5], tS5, cS.R[4] * tS4);
        float a3 = fmaf(cS.R[7], tS7, cS.R[6] * tS6);
        float sdS = (a0 + a1) + (a2 + a3);
        float e0 = fmaf(cE.R[1], tE1, cE.R[0] * tE0);
        float e1 = fmaf(cE.R[3], tE3, cE.R[2] * tE2);
        float e2 = fmaf(cE.R[5], tE5, cE.R[4] * tE4);
        float e3 = fmaf(cE.R[7], tE7, cE.R[6] * tE6);
        float sdE = (e0 + e1) + (e2 + e3);

        float sS0 = RLF(sdS, 0), sS1 = RLF(sdS, 1), sS2 = RLF(sdS, 2), sS3 = RLF(sdS, 3);
        float sS4 = RLF(sdS, 4), sS5 = RLF(sdS, 5), sS6 = RLF(sdS, 6), sS7 = RLF(sdS, 7);
        float sE0 = RLF(sdE, 0), sE1 = RLF(sdE, 1), sE2 = RLF(sdE, 2), sE3 = RLF(sdE, 3);
        float sE4 = RLF(sdE, 4), sE5 = RLF(sdE, 5), sE6 = RLF(sdE, 6), sE7 = RLF(sdE, 7);

        // ==== u updates + braw issues (2-body slack via tv2 pipeline) ====
        float dA = fmaf(cS.grow[0], sS0, fmaf(cS.grow[1], sS1, fmaf(cS.grow[2], sS2, cS.grow[3] * sS3)));
        float dB = fmaf(cS.grow[4], sS4, fmaf(cS.grow[5], sS5, fmaf(cS.grow[6], sS6, cS.grow[7] * sS7)));
        uS -= (dA + dB);
        float dC = fmaf(cE.grow[0], sE0, fmaf(cE.grow[1], sE1, fmaf(cE.grow[2], sE2, cE.grow[3] * sE3)));
        float dD = fmaf(cE.grow[4], sE4, fmaf(cE.grow[5], sE5, fmaf(cE.grow[6], sE6, cE.grow[7] * sE7)));
        uE -= (dC + dD);
        cS.braw = __shfl(uS, tv2, 64);
        cE.braw = __shfl(uE, tv2, 64);

        // ==== wacc[tok_j] += s_j  (shared compares; 2 partials per chain) ====
        waccS0 += (lane == cT.tk[0]) ? sS0 : 0.0f;
        waccE0 += (lane == cT.tk[0]) ? sE0 : 0.0f;
        waccS1 += (lane == cT.tk[1]) ? sS1 : 0.0f;
        waccE1 += (lane == cT.tk[1]) ? sE1 : 0.0f;
        waccS0 += (lane == cT.tk[2]) ? sS2 : 0.0f;
        waccE0 += (lane == cT.tk[2]) ? sE2 : 0.0f;
        waccS1 += (lane == cT.tk[3]) ? sS3 : 0.0f;
        waccE1 += (lane == cT.tk[3]) ? sE3 : 0.0f;
        waccS0 += (lane == cT.tk[4]) ? sS4 : 0.0f;
        waccE0 += (lane == cT.tk[4]) ? sE4 : 0.0f;
        waccS1 += (lane == cT.tk[5]) ? sS5 : 0.0f;
        waccE1 += (lane == cT.tk[5]) ? sE5 : 0.0f;
        waccS0 += (lane == cT.tk[6]) ? sS6 : 0.0f;
        waccE0 += (lane == cT.tk[6]) ? sE6 : 0.0f;
        waccS1 += (lane == cT.tk[7]) ? sS7 : 0.0f;
        waccE1 += (lane == cT.tk[7]) ? sE7 : 0.0f;

        // ==== rotate ====
        cT.tokv = tv2; tv2 = tv3;
        spS0 = sS0; spS1 = sS1; spS2 = sS2; spS3 = sS3;
        spS4 = sS4; spS5 = sS5; spS6 = sS6; spS7 = sS7;
        spE0 = sE0; spE1 = sE1; spE2 = sE2; spE3 = sE3;
        spE4 = sE4; spE5 = sE5; spE6 = sE6; spE7 = sE7;
    };

    for (int c = 255; c >= 1; c -= 2) {
        body2(TA, TB, SA, SB, EA, EB, c);
        body2(TB, TA, SB, SA, EB, EA, c - 1);
    }

    wacc_s[0][lane] = waccS0 + waccS1;
    wacc_s[1][lane] = waccE0 + waccE1;
    __syncthreads();

    // r[w2][rho] = sum_tok wacc[w2][tok] * v[w2][tok][rho]
    {
        const int w2  = lane >> 5;
        const int rho = lane & 31;
        const float* vv = ws + 4096 + w2 * 2048;
        const float* wa = &wacc_s[w2][0];
        float acc = 0.0f;
        #pragma unroll 8
        for (int tok = 0; tok < 64; ++tok) acc = fmaf(wa[tok], vv[tok * 32 + rho], acc);
        r_s[lane] = acc;
    }
    __syncthreads();

    // out = (r @ Wrp.T + brp) @ Wo.T + bo
    {
        float acc = brp[lane];
        #pragma unroll 8
        for (int m = 0; m < 64; ++m) acc = fmaf(Wrp[lane * 64 + m], r_s[m], acc);
        t1_s[lane] = acc;
    }
    __syncthreads();
    {
        float acc = bo[lane];
        #pragma unroll 8
        for (int m = 0; m < 64; ++m) acc = fmaf(Wo[lane * 64 + m], t1_s[m], acc);
        out[b * 64 + lane] = acc;
    }
}

extern "C" void kernel_launch(void* const* d_in, const int* in_sizes, int n_in,
                              void* d_out, int out_size, void* d_ws, size_t ws_size,
                              hipStream_t stream)
{
    const int*   seq   = (const int*)  d_in[0];
    const float* embed = (const float*)d_in[1];
    const float* W1    = (const float*)d_in[2];
    const float* b1    = (const float*)d_in[3];
    const float* W2    = (const float*)d_in[4];
    const float* b2    = (const float*)d_in[5];
    const float* ln_g  = (const float*)d_in[6];
    const float* ln_b  = (const float*)d_in[7];
    const float* Ws    = (const float*)d_in[8];
    const float* bs    = (const float*)d_in[9];
    const float* We    = (const float*)d_in[10];
    const float* be    = (const float*)d_in[11];
    const float* Wrp   = (const float*)d_in[12];
    const float* brp   = (const float*)d_in[13];
    const float* Wo    = (const float*)d_in[14];
    const float* bo    = (const float*)d_in[15];
    float* ws  = (float*)d_ws;
    float* out = (float*)d_out;

    hipLaunchKernelGGL(vocab_kernel, dim3(VOCAB), dim3(64), 0, stream,
                       embed, W1, b1, W2, b2, ln_g, ln_b, Ws, bs, We, be, ws);
    hipLaunchKernelGGL(gram_kernel, dim3(8), dim3(256), 0, stream, ws);
    hipLaunchKernelGGL(scan_kernel, dim3(BATCH), dim3(64), 0, stream,
                       seq, ws, Wrp, brp, Wo, bo, out);
}

// Round 5
// 193.679 us; speedup vs baseline: 1.2491x; 1.2491x over previous
//
#include <hip/hip_runtime.h>

#define HIDDEN 64
#define HALFD  32
#define VOCAB  64
#define BATCH  256
#define SEQLEN 2048

#define RLF(v, sl) __int_as_float(__builtin_amdgcn_readlane(__float_as_int(v), (sl)))
#define RLI(v, sl) __builtin_amdgcn_readlane((v), (sl))
// lane-j broadcast within each 32-lane half (valid here: value is 8-periodic)
#define SWZF(v, j) __int_as_float(__builtin_amdgcn_ds_swizzle(__float_as_int(v), ((j) << 5)))
#define GIX(j,m) (((j)==0?0:(j)==1?7:(j)==2?13:(j)==3?18:(j)==4?22:(j)==5?25:27) + (m) - (j) - 1)
#define OM(m) (((m)*((m)+1))>>1)

// ---------------------------------------------------------------------------
// Kernel 1 (R20): per-token vocab tables, LDS-staged weights.
// Old version read W1[tid*64+m] (lane=row, m=col) -> 64 cache lines per load
// instruction. Now: coalesced float4 global loads into padded LDS (strides
// 65/129/65 -> bank (i+m)%32, conflict-free), staging overlapped with
// compute phases across the 256-thread block.
//   ws[0    ..2047]  ks_voc [64][32]  (normalized hs)
//   ws[2048 ..4095]  ke_voc [64][32]  (normalized he)
//   ws[4096 ..6143]  vs_voc [64][32]  (raw hs)
//   ws[6144 ..8191]  ve_voc [64][32]  (raw he)
//   ws[8192 ..16383] Gs,Ge [2][64][64]
// ---------------------------------------------------------------------------
__global__ __launch_bounds__(256) void vocab_kernel(
    const float* __restrict__ embed, const float* __restrict__ W1, const float* __restrict__ b1,
    const float* __restrict__ W2, const float* __restrict__ b2,
    const float* __restrict__ ln_g, const float* __restrict__ ln_b,
    const float* __restrict__ Ws, const float* __restrict__ bs,
    const float* __restrict__ We, const float* __restrict__ be,
    float* __restrict__ ws)
{
    const int v = blockIdx.x;
    const int tid = threadIdx.x;

    __shared__ float e_s[64];
    __shared__ float W1_s[128][65];
    __shared__ float W2_s[64][129];
    __shared__ float Wse_s[64][65];   // rows 0..31 = Ws, rows 32..63 = We
    __shared__ float a1_s[128];
    __shared__ float h_s[64];

    if (tid < 64) e_s[tid] = embed[v * 64 + tid];
    // stage W1 (128x64): 2048 float4 loads, coalesced
    {
        const float4* src = (const float4*)W1;
        for (int i = tid; i < 2048; i += 256) {
            float4 x4 = src[i];
            const int e = i << 2, r = e >> 6, c = e & 63;
            W1_s[r][c] = x4.x; W1_s[r][c+1] = x4.y; W1_s[r][c+2] = x4.z; W1_s[r][c+3] = x4.w;
        }
    }
    __syncthreads();

    // phase 2: tid<128 compute a1; tid>=128 stage W2 (64x128)
    if (tid < 128) {
        float p0 = b1[tid], p1 = 0.f, p2 = 0.f, p3 = 0.f;
        #pragma unroll
        for (int m = 0; m < 64; m += 4) {
            p0 = fmaf(e_s[m],   W1_s[tid][m],   p0);
            p1 = fmaf(e_s[m+1], W1_s[tid][m+1], p1);
            p2 = fmaf(e_s[m+2], W1_s[tid][m+2], p2);
            p3 = fmaf(e_s[m+3], W1_s[tid][m+3], p3);
        }
        a1_s[tid] = fmaxf((p0 + p1) + (p2 + p3), 0.0f);
    } else {
        const float4* src = (const float4*)W2;
        for (int i = tid - 128; i < 2048; i += 128) {
            float4 x4 = src[i];
            const int e = i << 2, r = e >> 7, c = e & 127;
            W2_s[r][c] = x4.x; W2_s[r][c+1] = x4.y; W2_s[r][c+2] = x4.z; W2_s[r][c+3] = x4.w;
        }
    }
    __syncthreads();

    // phase 3: tid<64 compute ff + LayerNorm (wave 0); tid 64..191 stage Ws/We
    if (tid < 64) {
        float f0 = b2[tid], f1 = 0.f, f2 = 0.f, f3 = 0.f;
        #pragma unroll
        for (int m = 0; m < 128; m += 4) {
            f0 = fmaf(a1_s[m],   W2_s[tid][m],   f0);
            f1 = fmaf(a1_s[m+1], W2_s[tid][m+1], f1);
            f2 = fmaf(a1_s[m+2], W2_s[tid][m+2], f2);
            f3 = fmaf(a1_s[m+3], W2_s[tid][m+3], f3);
        }
        float x = e_s[tid] + ((f0 + f1) + (f2 + f3));
        float s = x, s2 = x * x;
        #pragma unroll
        for (int off = 32; off >= 1; off >>= 1) {
            s  += __shfl_xor(s,  off, 64);
            s2 += __shfl_xor(s2, off, 64);
        }
        float mu  = s * (1.0f / 64.0f);
        float var = s2 * (1.0f / 64.0f) - mu * mu;
        h_s[tid] = (x - mu) * rsqrtf(var + 1e-5f) * ln_g[tid] + ln_b[tid];
    } else if (tid < 192) {
        const int t2 = tid - 64;
        const float4* s1 = (const float4*)Ws;
        const float4* s2 = (const float4*)We;
        for (int i = t2; i < 512; i += 128) {
            float4 x4 = s1[i];
            const int e = i << 2, r = e >> 6, c = e & 63;
            Wse_s[r][c] = x4.x; Wse_s[r][c+1] = x4.y; Wse_s[r][c+2] = x4.z; Wse_s[r][c+3] = x4.w;
        }
        for (int i = t2; i < 512; i += 128) {
            float4 x4 = s2[i];
            const int e = i << 2, r = e >> 6, c = e & 63;
            Wse_s[32+r][c] = x4.x; Wse_s[32+r][c+1] = x4.y; Wse_s[32+r][c+2] = x4.z; Wse_s[32+r][c+3] = x4.w;
        }
    }
    __syncthreads();

    // phase 4: tid<64 (wave 0) compute hs/he + normalize + store
    if (tid < 64) {
        const int j = tid & 31;
        const bool is_s = tid < 32;
        float c0 = is_s ? bs[j] : be[j];
        float c1 = 0.f, c2 = 0.f, c3 = 0.f;
        #pragma unroll
        for (int m = 0; m < 64; m += 4) {
            c0 = fmaf(h_s[m],   Wse_s[tid][m],   c0);
            c1 = fmaf(h_s[m+1], Wse_s[tid][m+1], c1);
            c2 = fmaf(h_s[m+2], Wse_s[tid][m+2], c2);
            c3 = fmaf(h_s[m+3], Wse_s[tid][m+3], c3);
        }
        float acc = (c0 + c1) + (c2 + c3);

        float n2 = acc * acc;
        #pragma unroll
        for (int off = 16; off >= 1; off >>= 1) n2 += __shfl_xor(n2, off, 64);
        float norm = sqrtf(n2);
        float kn = acc / fmaxf(norm, 1e-12f);

        const int base = v * 32 + j;
        if (is_s) { ws[base]        = kn; ws[4096 + base] = acc; }
        else      { ws[2048 + base] = kn; ws[6144 + base] = acc; }
    }
}

// ---------------------------------------------------------------------------
// Kernel 1b: Gram tables G_w[a][b] = k_w[a].k_w[b], [64][64] in ws.
// ---------------------------------------------------------------------------
__global__ __launch_bounds__(256) void gram_kernel(float* __restrict__ ws)
{
    const int w   = blockIdx.x & 1;
    const int seg = blockIdx.x >> 1;          // 0..3
    const int tid = threadIdx.x;
    __shared__ float k_s[64][33];
    const float* kb = ws + w * 2048;
    for (int i = tid; i < 2048; i += 256) k_s[i >> 5][i & 31] = kb[i];
    __syncthreads();
    const int a  = seg * 16 + (tid >> 4);
    const int b0 = (tid & 15) << 2;
    float* Gw = ws + 8192 + w * 4096 + a * 64;
    #pragma unroll
    for (int bb = 0; bb < 4; ++bb) {
        const int bcol = b0 + bb;
        float acc0 = 0.f, acc1 = 0.f;
        #pragma unroll
        for (int m = 0; m < 32; m += 2) {
            acc0 = fmaf(k_s[a][m],     k_s[bcol][m],     acc0);
            acc1 = fmaf(k_s[a][m + 1], k_s[bcol][m + 1], acc1);
        }
        Gw[bcol] = acc0 + acc1;
    }
}

// chunk-8 solve-matrix build: s = W t with f folded (verbatim R9 math)
static __device__ __forceinline__ void build_wpack(
    const int* tj, float fb, float invL, bool is_e, bool is_last, float* Wp,
    const float* __restrict__ Gg)
{
    float f[8];
    #pragma unroll
    for (int j = 0; j < 8; ++j) f[j] = is_e ? (fb + (float)j * invL) : 1.0f;
    if (is_last) f[7] = 0.0f;     // position 2047 is the query, not a write

    float g[28];
    #pragma unroll
    for (int j = 0; j < 7; ++j)
        #pragma unroll
        for (int m = j + 1; m < 8; ++m) g[GIX(j, m)] = Gg[tj[j] * 64 + tj[m]];

    #pragma unroll
    for (int m = 0; m < 8; ++m) {
        float col[8];
        col[m] = f[m];
        #pragma unroll
        for (int j = 6; j >= 0; --j) {
            if (j < m) {
                float acc = 0.0f;
                #pragma unroll
                for (int p = 1; p < 8; ++p)
                    if (p > j && p <= m) acc = fmaf(g[GIX(j, p)], col[p], acc);
                col[j] = -f[j] * acc;
            }
        }
        #pragma unroll
        for (int j = 0; j < 8; ++j)
            if (j <= m) Wp[OM(m) + j] = col[j];
    }
}

struct Chunk {
    int   tokv;      // lane-vector: tok[c*8 + (lane&7)]
    int   tk[8];     // uniform tokens of this chunk (SGPR via v_readlane)
    float grow[8];   // G[tok_j][lane]
    float R[8];      // per-lane W row: lane l7=i holds R_i[m]=Wp[OM(m)+i] (m>=i)
    float braw;      // corrected-gather input: shfl(u_{c+1}, tok_c), 2-body slack
    float bp[8];     // correction Gram block: G[tk_{c+1,j}][tk_{c,l7}], bpermute 1-body early
};

// ---------------------------------------------------------------------------
// Kernel 2 (R21): R17(=R1, 101.3us) structure with the readlane broadcasts
// replaced by ds_swizzle broadcasts.
// Evidence: body time ~950cyc invariant under slack/queue/instr-count changes
// (R0..R2); the invariant is the ~32 v_readlane SGPR-hazard points. tl and sd
// are 8-periodic across lanes, so t_j/s_j broadcasts = ds_swizzle(or_mask=j)
// (LDS crossbar, no SGPR, pipelined, bit-identical). bp stays on the bpermute
// path (R1) but issues EARLY to fill swizzle latency. tk readlanes stay
// (needed as SGPR for coalesced grow addressing; off-spine).
// ---------------------------------------------------------------------------
__global__ __launch_bounds__(128) void scan_kernel(
    const int* __restrict__ seq, const float* __restrict__ ws,
    const float* __restrict__ Wrp, const float* __restrict__ brp,
    const float* __restrict__ Wo, const float* __restrict__ bo,
    float* __restrict__ out)
{
    const int b    = blockIdx.x;
    const int tid  = threadIdx.x;        // 0..127
    const int w    = tid >> 6;           // wave: 0 = s-branch, 1 = e-branch
    const int lane = tid & 63;
    const int l7   = lane & 7;
    const bool is_e = (w == 1);

    __shared__ __align__(16) float Wlds[2][256][8][8];   // 128 KB
    __shared__ __align__(16) int   toklds[SEQLEN];       // 8 KB (prologue only)
    __shared__ float wacc_s[2][64];
    __shared__ float r_s[64];
    __shared__ float t1_s[64];

    const float* Gg = ws + 8192 + w * 4096;
    const int*   sq = seq + b * SEQLEN;

    // ---- stage token sequence (for the W-build prologue) ----
    {
        const int4* sq4 = (const int4*)sq;
        int4* tl = (int4*)toklds;
        #pragma unroll
        for (int i = 0; i < 4; ++i) tl[tid + i * 128] = sq4[tid + i * 128];
    }
    __syncthreads();

    // ---- precompute W row-tables: lanes parallel over chunks (4 per lane) ----
    {
        const float invL = 1.0f / (float)SEQLEN;
        #pragma unroll
        for (int qq = 0; qq < 4; ++qq) {
            const int c = lane + (qq << 6);
            int tj[8];
            #pragma unroll
            for (int j = 0; j < 8; ++j) tj[j] = toklds[c * 8 + j];
            float Wp[36];
            build_wpack(tj, (float)(8 * c + 1) * invL, invL, is_e, c == 255, Wp, Gg);
            const int cx = c & 7;
            #pragma unroll
            for (int i = 0; i < 8; ++i) {
                float r[8];
                #pragma unroll
                for (int m = 0; m < 8; ++m) r[m] = (m >= i) ? Wp[OM(m) + i] : 0.0f;
                float4* dst = (float4*)&Wlds[w][c][i ^ cx][0];
                dst[0] = make_float4(r[0], r[1], r[2], r[3]);
                dst[1] = make_float4(r[4], r[5], r[6], r[7]);
            }
        }
    }
    __syncthreads();

    // ---- serial backward sweep ----
    Chunk A, B;
    float u, wacc0 = 0.0f, wacc1 = 0.0f;
    float sp0, sp1, sp2, sp3, sp4, sp5, sp6, sp7;

    // prologue: chunk 255 fully; chunk 254 tokens + braw + bp; chunk 253 tokens
    A.tokv = sq[2040 + l7];
    B.tokv = sq[2032 + l7];
    int tv2 = sq[2024 + l7];
    #pragma unroll
    for (int j = 0; j < 8; ++j) A.tk[j] = RLI(A.tokv, j);
    #pragma unroll
    for (int j = 0; j < 8; ++j) A.grow[j] = Gg[A.tk[j] * 64 + lane];
    {
        const float4* rp = (const float4*)&Wlds[w][255][l7 ^ 7][0];
        float4 lo = rp[0], hi = rp[1];
        A.R[0] = lo.x; A.R[1] = lo.y; A.R[2] = lo.z; A.R[3] = lo.w;
        A.R[4] = hi.x; A.R[5] = hi.y; A.R[6] = hi.z; A.R[7] = hi.w;
    }
    u = Gg[A.tk[7] * 64 + lane];           // query token = position 2047
    A.braw = __shfl(u, A.tokv, 64);        // t_255 raw (corr = 0)
    B.braw = __shfl(u, B.tokv, 64);        // braw'_254 = shfl(u_255, tok_254)
    #pragma unroll
    for (int j = 0; j < 8; ++j) {
        A.bp[j] = 0.0f;
        B.bp[j] = __shfl(A.grow[j], B.tokv, 64);   // G[tk255_j][tk254_l7]
    }
    sp0 = sp1 = sp2 = sp3 = sp4 = sp5 = sp6 = sp7 = 0.0f;

    auto body = [&](Chunk& cur, Chunk& nxt, int c) {
        const int cm1 = (c > 0) ? c - 1 : 0;
        const int cm3 = (c > 2) ? c - 3 : 0;

        // ---- spine head: corrected gather  t = braw' - bp . s_prev ----
        float c01 = fmaf(cur.bp[1], sp1, cur.bp[0] * sp0);
        float c23 = fmaf(cur.bp[3], sp3, cur.bp[2] * sp2);
        float c45 = fmaf(cur.bp[5], sp5, cur.bp[4] * sp4);
        float c67 = fmaf(cur.bp[7], sp7, cur.bp[6] * sp6);
        float tl = cur.braw - ((c01 + c23) + (c45 + c67));

        // ---- t broadcast: ds_swizzle lane-j bcast (no SGPR hazard) ----
        float t0 = SWZF(tl, 0), t1 = SWZF(tl, 1), t2 = SWZF(tl, 2), t3 = SWZF(tl, 3);
        float t4 = SWZF(tl, 4), t5 = SWZF(tl, 5), t6 = SWZF(tl, 6), t7 = SWZF(tl, 7);

        // ---- prefetch chunk c-1 into nxt (fills swizzle latency) ----
        #pragma unroll
        for (int j = 0; j < 8; ++j) nxt.bp[j] = __shfl(cur.grow[j], nxt.tokv, 64);
        #pragma unroll
        for (int j = 0; j < 8; ++j) nxt.tk[j] = RLI(nxt.tokv, j);
        #pragma unroll
        for (int j = 0; j < 8; ++j) nxt.grow[j] = Gg[nxt.tk[j] * 64 + lane];
        {
            const float4* rp = (const float4*)&Wlds[w][cm1][l7 ^ (cm1 & 7)][0];
            float4 lo = rp[0], hi = rp[1];
            nxt.R[0] = lo.x; nxt.R[1] = lo.y; nxt.R[2] = lo.z; nxt.R[3] = lo.w;
            nxt.R[4] = hi.x; nxt.R[5] = hi.y; nxt.R[6] = hi.z; nxt.R[7] = hi.w;
        }
        int tv3 = sq[cm3 * 8 + l7];          // tokens of chunk c-3 (per-lane VMEM)

        // ---- spine: distributed s (lane l7=i computes s_i) ----
        const float* R = cur.R;
        float a0 = fmaf(R[1], t1, R[0] * t0);
        float a1 = fmaf(R[3], t3, R[2] * t2);
        float a2 = fmaf(R[5], t5, R[4] * t4);
        float a3 = fmaf(R[7], t7, R[6] * t6);
        float sd = (a0 + a1) + (a2 + a3);

        // ---- s broadcast: ds_swizzle ----
        float s0 = SWZF(sd, 0), s1 = SWZF(sd, 1), s2 = SWZF(sd, 2), s3 = SWZF(sd, 3);
        float s4 = SWZF(sd, 4), s5 = SWZF(sd, 5), s6 = SWZF(sd, 6), s7 = SWZF(sd, 7);

        // ---- u update, then braw for chunk c-2 (2-body slack) ----
        float dA = fmaf(cur.grow[0], s0, fmaf(cur.grow[1], s1, fmaf(cur.grow[2], s2, cur.grow[3] * s3)));
        float dB = fmaf(cur.grow[4], s4, fmaf(cur.grow[5], s5, fmaf(cur.grow[6], s6, cur.grow[7] * s7)));
        u -= (dA + dB);
        cur.braw = __shfl(u, tv2, 64);       // braw'_{c-2} = shfl(u_{c-1}, tok_{c-2})

        // ---- wacc[tok_j] += s_j  (lane = token; off-spine, 2 partials) ----
        wacc0 += (lane == cur.tk[0]) ? s0 : 0.0f;
        wacc1 += (lane == cur.tk[1]) ? s1 : 0.0f;
        wacc0 += (lane == cur.tk[2]) ? s2 : 0.0f;
        wacc1 += (lane == cur.tk[3]) ? s3 : 0.0f;
        wacc0 += (lane == cur.tk[4]) ? s4 : 0.0f;
        wacc1 += (lane == cur.tk[5]) ? s5 : 0.0f;
        wacc0 += (lane == cur.tk[6]) ? s6 : 0.0f;
        wacc1 += (lane == cur.tk[7]) ? s7 : 0.0f;

        // ---- rotate pipeline registers ----
        cur.tokv = tv2; tv2 = tv3;
        sp0 = s0; sp1 = s1; sp2 = s2; sp3 = s3;
        sp4 = s4; sp5 = s5; sp6 = s6; sp7 = s7;
    };

    for (int c = 255; c >= 1; c -= 2) {
        body(A, B, c);
        body(B, A, c - 1);
    }

    wacc_s[w][lane] = wacc0 + wacc1;
    __syncthreads();

    // r[w2][rho] = sum_tok wacc[w2][tok] * v[w2][tok][rho]  (v from global ws)
    if (tid < 64) {
        const int w2  = tid >> 5;
        const int rho = tid & 31;
        const float* vv = ws + 4096 + w2 * 2048;
        const float* wa = &wacc_s[w2][0];
        float acc = 0.0f;
        #pragma unroll 8
        for (int tok = 0; tok < 64; ++tok) acc = fmaf(wa[tok], vv[tok * 32 + rho], acc);
        r_s[tid] = acc;
    }
    __syncthreads();

    // out = (r @ Wrp.T + brp) @ Wo.T + bo
    if (tid < 64) {
        float acc = brp[tid];
        #pragma unroll 8
        for (int m = 0; m < 64; ++m) acc = fmaf(Wrp[tid * 64 + m], r_s[m], acc);
        t1_s[tid] = acc;
    }
    __syncthreads();
    if (tid < 64) {
        float acc = bo[tid];
        #pragma unroll 8
        for (int m = 0; m < 64; ++m) acc = fmaf(Wo[tid * 64 + m], t1_s[m], acc);
        out[b * 64 + tid] = acc;
    }
}

extern "C" void kernel_launch(void* const* d_in, const int* in_sizes, int n_in,
                              void* d_out, int out_size, void* d_ws, size_t ws_size,
                              hipStream_t stream)
{
    const int*   seq   = (const int*)  d_in[0];
    const float* embed = (const float*)d_in[1];
    const float* W1    = (const float*)d_in[2];
    const float* b1    = (const float*)d_in[3];
    const float* W2    = (const float*)d_in[4];
    const float* b2    = (const float*)d_in[5];
    const float* ln_g  = (const float*)d_in[6];
    const float* ln_b  = (const float*)d_in[7];
    const float* Ws    = (const float*)d_in[8];
    const float* bs    = (const float*)d_in[9];
    const float* We    = (const float*)d_in[10];
    const float* be    = (const float*)d_in[11];
    const float* Wrp   = (const float*)d_in[12];
    const float* brp   = (const float*)d_in[13];
    const float* Wo    = (const float*)d_in[14];
    const float* bo    = (const float*)d_in[15];
    float* ws  = (float*)d_ws;
    float* out = (float*)d_out;

    hipLaunchKernelGGL(vocab_kernel, dim3(VOCAB), dim3(256), 0, stream,
                       embed, W1, b1, W2, b2, ln_g, ln_b, Ws, bs, We, be, ws);
    hipLaunchKernelGGL(gram_kernel, dim3(8), dim3(256), 0, stream, ws);
    hipLaunchKernelGGL(scan_kernel, dim3(BATCH), dim3(128), 0, stream,
                       seq, ws, Wrp, brp, Wo, bo, out);
}